// Round 11
// baseline (71.531 us; speedup 1.0000x reference)
//
#include <hip/hip_runtime.h>

// Problem dims: B=2, b=16, t_q=64, t_k=128, d=512, slices = 32
// d_out = context [32][64][512] f32 ++ scores_normalized [32][64][128] f32
// d_ws: pqT [32][64][512] (4MB, t-major!) ++ pkT [32][512][128] (8MB, n-major)
//       ++ X16 (8MB f16) ++ wtab[513] (@20MB)

#define DEV_INLINE __device__ __forceinline__

constexpr float C2    = 2.8853900817779268f;  // 2*log2(e)
constexpr float LOG2E = 1.4426950408889634f;

typedef _Float16 f16x8 __attribute__((ext_vector_type(8)));
typedef float    f32x16 __attribute__((ext_vector_type(16)));

DEV_INLINE unsigned int pk2(float a, float b) {
    auto h = __builtin_amdgcn_cvt_pkrtz(a, b);
    return __builtin_bit_cast(unsigned int, h);
}

// Newton reciprocal (pure VALU, rel err ~6e-6)
DEV_INLINE float rcp_nr(float d) {
    float y = __builtin_bit_cast(float, 0x7EF311C3u - __builtin_bit_cast(unsigned int, d));
    y = y * (2.0f - d * y);
    y = y * (2.0f - d * y);
    return y;
}

#define GL2LDS16(g, l) __builtin_amdgcn_global_load_lds( \
    (const __attribute__((address_space(1))) void*)(g),  \
    (__attribute__((address_space(3))) void*)(l), 16, 0, 0)

DEV_INLINE float wave_rsum(float v) {
#pragma unroll
    for (int off = 32; off; off >>= 1) v += __shfl_xor(v, off, 64);
    return v;
}
DEV_INLINE float wave_rmax(float v) {
#pragma unroll
    for (int off = 32; off; off >>= 1) v = fmaxf(v, __shfl_xor(v, off, 64));
    return v;
}

// ---------------------------------------------------------------------------
// One-shot f32 -> f16 conversion + wtab build (block 4096).
// ---------------------------------------------------------------------------
__global__ __launch_bounds__(256)
void cvt_f16_kernel(const float* __restrict__ query, const float* __restrict__ keys,
                    const float* __restrict__ Wq,    const float* __restrict__ Wk,
                    const float* __restrict__ vatt,
                    uint2* __restrict__ dst, float* __restrict__ wtab)
{
    if (blockIdx.x == 4096) {
        const int t = threadIdx.x;
        wtab[t] = -2.f * vatt[t]; wtab[t + 256] = -2.f * vatt[t + 256];
        return;
    }
    const int i4 = blockIdx.x * 256 + threadIdx.x;
    const float* src; int base;
    if (i4 < 262144)      { src = query; base = 0; }
    else if (i4 < 786432) { src = keys;  base = 262144; }
    else if (i4 < 917504) { src = Wq;    base = 786432; }
    else                  { src = Wk;    base = 917504; }
    const float4 v = *reinterpret_cast<const float4*>(src + (size_t)(i4 - base) * 4);
    dst[i4] = make_uint2(pk2(v.x, v.y), pk2(v.z, v.w));
}

// ---------------------------------------------------------------------------
// fp16 MFMA projection GEMM.  Machinery identical to R4-validated kernel.
// Query branch SWAPPED: A = query16 (128 t-rows), B = Wq16 (64 n-rows)
//   -> D[t][n] -> pqT[slice][t 64][n 512]  (t-major, coalesced over n)
// Keys branch unchanged: A = Wk16 (128 n), B = keys16 (64 t)
//   -> D[n][t] -> pkT[slice][n 512][k 128]
// Blocks 0..127: query. 128..383: keys.
// ---------------------------------------------------------------------------
__global__ __launch_bounds__(256)
void proj_mfma_kernel(const _Float16* __restrict__ X16,
                      float* __restrict__ pqT, float* __restrict__ pkT)
{
    __shared__ __align__(16) unsigned char smem[24576];   // 2 x (A 8KB + B 4KB)

    // bijective chunked XCD swizzle (384 % 8 == 0)
    const int bid = (blockIdx.x & 7) * 48 + (blockIdx.x >> 3);

    int Bi, i128, i64;         // i128: A-tile idx, i64: B-tile idx
    bool qswap;
    const _Float16 *Ab, *Bb;
    if (bid < 128) {           // query GEMM (swapped)
        Bi = bid >> 6; const int r = bid & 63;
        i128 = r >> 3;         // t-tile (8 per B)
        i64  = r & 7;          // n-tile
        Ab = X16 + ((size_t)Bi * 1024 + i128 * 128) * 512;            // query rows
        Bb = X16 + 3145728 + (size_t)Bi * 262144 + (size_t)(i64 * 64) * 512; // Wq rows
        qswap = true;
    } else {                   // keys GEMM (original orientation)
        const int b2 = bid - 128;
        Bi = b2 >> 7; i128 = (b2 >> 5) & 3; i64 = b2 & 31;
        Ab = X16 + 3670016 + (size_t)Bi * 262144 + (size_t)(i128 * 128) * 512; // Wk rows
        Bb = X16 + 1048576 + ((size_t)Bi * 2048 + i64 * 64) * 512;            // keys rows
        qswap = false;
    }
    const int tid = threadIdx.x;

    auto srcoff = [](int u) {
        const int row = u >> 2, s = (u & 3) ^ ((row >> 1) & 3);
        return (size_t)row * 512 + s * 8;
    };
    const _Float16* gA0 = Ab + srcoff(tid);         // A rows 0..63
    const _Float16* gA1 = Ab + srcoff(tid + 256);   // A rows 64..127
    const _Float16* gB  = Bb + srcoff(tid);         // B rows 0..63
    unsigned char* const ldsA0 = smem + tid * 16;
    unsigned char* const ldsA1 = smem + 4096 + tid * 16;
    unsigned char* const ldsB  = smem + 8192 + tid * 16;

    const int wid = tid >> 6, lane = tid & 63;
    const int wm = wid >> 1, wn = wid & 1;
    const int r31 = lane & 31, h = lane >> 5;
    auto lofs = [](int row, int slot) {
        return row * 64 + ((slot ^ ((row >> 1) & 3)) * 16);
    };
    const int rowA0 = wm * 64 + r31, rowA1 = rowA0 + 32, rowB = wn * 32 + r31;
    const int a00 = lofs(rowA0, h),     a01 = lofs(rowA0, 2 + h);
    const int a10 = lofs(rowA1, h),     a11 = lofs(rowA1, 2 + h);
    const int b0  = 8192 + lofs(rowB, h), b1 = 8192 + lofs(rowB, 2 + h);

    f32x16 acc0, acc1;
#pragma unroll
    for (int i = 0; i < 16; ++i) { acc0[i] = 0.f; acc1[i] = 0.f; }

    GL2LDS16(gA0, ldsA0);
    GL2LDS16(gA1, ldsA1);
    GL2LDS16(gB,  ldsB);
    asm volatile("s_waitcnt vmcnt(0)" ::: "memory");
    __builtin_amdgcn_s_barrier();

    for (int ks = 0; ks < 16; ++ks) {
        const int buf = ks & 1;
        if (ks < 15) {
            const int ko = (ks + 1) * 32, bo = (buf ^ 1) * 12288;
            GL2LDS16(gA0 + ko, ldsA0 + bo);
            GL2LDS16(gA1 + ko, ldsA1 + bo);
            GL2LDS16(gB  + ko, ldsB  + bo);
        }
        const unsigned char* sb = smem + buf * 12288;
        const f16x8 fa00 = *reinterpret_cast<const f16x8*>(sb + a00);
        const f16x8 fa01 = *reinterpret_cast<const f16x8*>(sb + a01);
        const f16x8 fa10 = *reinterpret_cast<const f16x8*>(sb + a10);
        const f16x8 fa11 = *reinterpret_cast<const f16x8*>(sb + a11);
        const f16x8 fb0  = *reinterpret_cast<const f16x8*>(sb + b0);
        const f16x8 fb1  = *reinterpret_cast<const f16x8*>(sb + b1);
        acc0 = __builtin_amdgcn_mfma_f32_32x32x16_f16(fa00, fb0, acc0, 0, 0, 0);
        acc0 = __builtin_amdgcn_mfma_f32_32x32x16_f16(fa01, fb1, acc0, 0, 0, 0);
        acc1 = __builtin_amdgcn_mfma_f32_32x32x16_f16(fa10, fb0, acc1, 0, 0, 0);
        acc1 = __builtin_amdgcn_mfma_f32_32x32x16_f16(fa11, fb1, acc1, 0, 0, 0);
        if (ks < 15) {
            asm volatile("s_waitcnt vmcnt(0)" ::: "memory");
            __builtin_amdgcn_s_barrier();
        }
    }

    // epilogue: D row = A-row expr, D col = B-row (lane r31)
#pragma unroll
    for (int ab = 0; ab < 2; ++ab) {
        const f32x16 acc = ab ? acc1 : acc0;
#pragma unroll
        for (int reg = 0; reg < 16; ++reg) {
            const int dr = (reg & 3) + 8 * (reg >> 2) + 4 * h;       // 0..31
            const int arow = wm * 64 + ab * 32 + dr;                  // A-tile row
            if (qswap) {
                const int trow = i128 * 128 + arow;                   // query row in B
                const int n    = i64 * 64 + wn * 32 + r31;
                const int slice = Bi * 16 + (trow >> 6), t = trow & 63;
                pqT[((size_t)(slice * 64 + t)) * 512 + n] = acc[reg] * C2;
            } else {
                const int nf   = i128 * 128 + arow;
                const int trow = i64 * 64 + wn * 32 + r31;            // keys row in B
                const int slice = Bi * 16 + (trow >> 7), t = trow & 127;
                pkT[((size_t)(slice * 512 + nf)) * 128 + t] = acc[reg] * C2;
            }
        }
    }
}

// ---------------------------------------------------------------------------
// Fused score + softmax + context.  256 blocks x 1024 threads.
// Block = (slice, q-tile of 8); thread = one (q,k) cell, all 512 n.
// pk staged in 32KB LDS chunks (global_load_lds dbuf); pq staged once (16KB);
// w via uniform s_load. Inner loop: zero global memory.
// sumv dropped (softmax shift-invariant).
// ---------------------------------------------------------------------------
__global__ __launch_bounds__(1024, 1)
void score_ctx_kernel(const float* __restrict__ pqT,   // [32][64][512] t-major
                      const float* __restrict__ pkT,   // [32][512][128]
                      const float* __restrict__ wtab,  // [512] = -2v
                      const float* __restrict__ keys,  // [32][128][512]
                      float* __restrict__ sc_out,      // [32][64][128]
                      float* __restrict__ ctx)         // [32][64][512]
{
    // bijective XCD swizzle (256 blocks): xcd owns 4 slices (32 blocks)
    const int wg = (blockIdx.x & 7) * 32 + (blockIdx.x >> 3);
    const int slice = wg >> 3;
    const int q0    = (wg & 7) * 8;
    const int tid   = threadIdx.x;
    const int q     = tid >> 7;     // 0..7
    const int k     = tid & 127;

    __shared__ __align__(16) float pkbuf[2][64][128];   // 64KB (reused as ctx tree)
    __shared__ __align__(16) float pqlq[8][512];        // 16KB
    __shared__ float scP[8][128];                       // 4KB
    __shared__ float red[16], red2[16];

    // stage pq tile: 4096 floats, thread loads 4 contiguous
    {
        const int f = tid * 4, qq = f >> 9, n0 = f & 511;
        const float4 v = *reinterpret_cast<const float4*>(
            pqT + ((size_t)(slice * 64 + q0 + qq)) * 512 + n0);
        *reinterpret_cast<float4*>(&pqlq[qq][n0]) = v;
    }
    // prologue: stage pk chunk 0 (rows n 0..63 = 32KB contiguous)
    const float* __restrict__ pkbase = pkT + (size_t)slice * 65536;
    {
        unsigned char* d = (unsigned char*)&pkbuf[0][0][0];
        GL2LDS16(pkbase + (size_t)tid * 4,        d + tid * 16);
        GL2LDS16(pkbase + 4096 + (size_t)tid * 4, d + 16384 + tid * 16);
    }
    __syncthreads();   // covers pql ds_writes + chunk0 vmcnt

    float a = 0.f;
    for (int c = 0; c < 8; ++c) {
        const int buf = c & 1;
        if (c < 7) {   // stage next chunk into other buffer
            unsigned char* d = (unsigned char*)&pkbuf[buf ^ 1][0][0];
            const float* g = pkbase + (size_t)(c + 1) * 8192;
            GL2LDS16(g + (size_t)tid * 4,        d + tid * 16);
            GL2LDS16(g + 4096 + (size_t)tid * 4, d + 16384 + tid * 16);
        }
#pragma unroll
        for (int nl4 = 0; nl4 < 16; ++nl4) {
            const float4 pq4 = *reinterpret_cast<const float4*>(&pqlq[q][c * 64 + nl4 * 4]);
            const float4 w4  = *reinterpret_cast<const float4*>(&wtab[c * 64 + nl4 * 4]);
            const float pqa[4] = {pq4.x, pq4.y, pq4.z, pq4.w};
            const float wa[4]  = {w4.x, w4.y, w4.z, w4.w};
#pragma unroll
            for (int j = 0; j < 4; ++j) {
                const float pk = pkbuf[buf][nl4 * 4 + j][k];    // b32, conflict-free
                const float e  = __builtin_amdgcn_exp2f(pqa[j] + pk) + 1.f;
                const float r  = (j < 2) ? __builtin_amdgcn_rcpf(e) : rcp_nr(e);
                a = fmaf(wa[j], r, a);
            }
        }
        if (c < 7) {
            asm volatile("s_waitcnt vmcnt(0)" ::: "memory");
            __builtin_amdgcn_s_barrier();
        }
    }

    // softmax over k=128 per q (2 waves per q-row); shift-invariant (no sumv)
    const int wid = tid >> 6;
    {
        const float m0 = wave_rmax(a);
        if ((tid & 63) == 0) red[wid] = m0;
    }
    __syncthreads();
    const float m = fmaxf(red[2 * q], red[2 * q + 1]);
    float e = __builtin_amdgcn_exp2f((a - m) * LOG2E);
    {
        const float s0 = wave_rsum(e);
        if ((tid & 63) == 0) red2[wid] = s0;
    }
    __syncthreads();
    const float s = red2[2 * q] + red2[2 * q + 1];
    const float p = e * __builtin_amdgcn_rcpf(s);
    sc_out[((size_t)(slice * 64 + q0 + q)) * 128 + k] = p;
    scP[q][k] = p;
    __syncthreads();

    // context: kg owns 16 k-rows; kv row loaded once, applied to 8 q's
    const int kg = tid >> 7, n4 = tid & 127;
    float4 acc[8];
#pragma unroll
    for (int i = 0; i < 8; ++i) acc[i] = make_float4(0.f, 0.f, 0.f, 0.f);
    const float* __restrict__ kb = keys + (size_t)slice * 65536 + (size_t)(kg * 16) * 512 + n4 * 4;
#pragma unroll 4
    for (int r = 0; r < 16; ++r) {
        const float4 kv = *reinterpret_cast<const float4*>(kb + (size_t)r * 512);
#pragma unroll
        for (int qq = 0; qq < 8; ++qq) {
            const float pv = scP[qq][kg * 16 + r];              // broadcast
            acc[qq].x = fmaf(pv, kv.x, acc[qq].x);
            acc[qq].y = fmaf(pv, kv.y, acc[qq].y);
            acc[qq].z = fmaf(pv, kv.z, acc[qq].z);
            acc[qq].w = fmaf(pv, kv.w, acc[qq].w);
        }
    }

    // tree-combine 8 kg-groups (reuse pkbuf as [4][8][128] float4 = 64KB)
    float4* ctxp = reinterpret_cast<float4*>(&pkbuf[0][0][0]);
    if (kg >= 4) {
#pragma unroll
        for (int qq = 0; qq < 8; ++qq) ctxp[((kg - 4) * 8 + qq) * 128 + n4] = acc[qq];
    }
    __syncthreads();
    if (kg < 4) {
#pragma unroll
        for (int qq = 0; qq < 8; ++qq) {
            const float4 o = ctxp[(kg * 8 + qq) * 128 + n4];
            acc[qq].x += o.x; acc[qq].y += o.y; acc[qq].z += o.z; acc[qq].w += o.w;
        }
    }
    __syncthreads();
    if (kg == 2 || kg == 3) {
#pragma unroll
        for (int qq = 0; qq < 8; ++qq) ctxp[((kg - 2) * 8 + qq) * 128 + n4] = acc[qq];
    }
    __syncthreads();
    if (kg < 2) {
#pragma unroll
        for (int qq = 0; qq < 8; ++qq) {
            const float4 o = ctxp[(kg * 8 + qq) * 128 + n4];
            acc[qq].x += o.x; acc[qq].y += o.y; acc[qq].z += o.z; acc[qq].w += o.w;
        }
    }
    __syncthreads();
    if (kg == 1) {
#pragma unroll
        for (int qq = 0; qq < 8; ++qq) ctxp[qq * 128 + n4] = acc[qq];
    }
    __syncthreads();
    if (kg == 0) {
#pragma unroll
        for (int qq = 0; qq < 8; ++qq) {
            const float4 o = ctxp[qq * 128 + n4];
            acc[qq].x += o.x; acc[qq].y += o.y; acc[qq].z += o.z; acc[qq].w += o.w;
            *reinterpret_cast<float4*>(
                ctx + ((size_t)(slice * 64 + q0 + qq)) * 512 + n4 * 4) = acc[qq];
        }
    }
}

// ---------------------------------------------------------------------------
extern "C" void kernel_launch(void* const* d_in, const int* in_sizes, int n_in,
                              void* d_out, int out_size, void* d_ws, size_t ws_size,
                              hipStream_t stream)
{
    const float* query = (const float*)d_in[0];
    const float* keys  = (const float*)d_in[1];
    const float* Wq    = (const float*)d_in[2];
    const float* Wk    = (const float*)d_in[3];
    const float* vatt  = (const float*)d_in[4];

    float* ctx_out = (float*)d_out;
    float* sc_out  = ctx_out + (size_t)32 * 64 * 512;

    float* pqT = (float*)d_ws;                                    // 4MB  [32][64][512]
    float* pkT = pqT + (size_t)32 * 64 * 512;                     // 8MB  [32][512][128]
    _Float16* X16 = (_Float16*)((char*)d_ws + 12 * 1024 * 1024);  // 8MB f16
    float* wtab = (float*)((char*)d_ws + 20 * 1024 * 1024);       // 512 f32

    cvt_f16_kernel<<<dim3(4097), 256, 0, stream>>>(query, keys, Wq, Wk, vatt,
                                                   (uint2*)X16, wtab);
    proj_mfma_kernel<<<dim3(384), 256, 0, stream>>>(X16, pqT, pkT);
    score_ctx_kernel<<<dim3(256), 1024, 0, stream>>>(pqT, pkT, wtab, keys, sc_out, ctx_out);
}

// Round 12
// 59.710 us; speedup vs baseline: 1.1980x; 1.1980x over previous
//
#include <hip/hip_runtime.h>

// Problem dims: B=2, b=16, t_q=64, t_k=128, d=512, slices = 32
// d_out = context [32][64][512] f32 ++ scores_normalized [32][64][128] f32
// d_ws: pqT [32][512][64] (4MB, n-major) ++ pkT [32][512][128] (8MB)
//       ++ X16 (8MB f16) ++ wtab[512] (@20MB: -2*vatt)

#define DEV_INLINE __device__ __forceinline__

constexpr float C2    = 2.8853900817779268f;  // 2*log2(e)
constexpr float LOG2E = 1.4426950408889634f;

typedef _Float16 f16x8 __attribute__((ext_vector_type(8)));
typedef float    f32x16 __attribute__((ext_vector_type(16)));

DEV_INLINE unsigned int pk2(float a, float b) {
    auto h = __builtin_amdgcn_cvt_pkrtz(a, b);
    return __builtin_bit_cast(unsigned int, h);
}

// Newton reciprocal (pure VALU, rel err ~6e-6)
DEV_INLINE float rcp_nr(float d) {
    float y = __builtin_bit_cast(float, 0x7EF311C3u - __builtin_bit_cast(unsigned int, d));
    y = y * (2.0f - d * y);
    y = y * (2.0f - d * y);
    return y;
}

#define GL2LDS16(g, l) __builtin_amdgcn_global_load_lds( \
    (const __attribute__((address_space(1))) void*)(g),  \
    (__attribute__((address_space(3))) void*)(l), 16, 0, 0)

DEV_INLINE float wave_rsum(float v) {
#pragma unroll
    for (int off = 32; off; off >>= 1) v += __shfl_xor(v, off, 64);
    return v;
}
DEV_INLINE float wave_rmax(float v) {
#pragma unroll
    for (int off = 32; off; off >>= 1) v = fmaxf(v, __shfl_xor(v, off, 64));
    return v;
}

// ---------------------------------------------------------------------------
// One-shot f32 -> f16 conversion + wtab (-2v) build (block 4096).
// ---------------------------------------------------------------------------
__global__ __launch_bounds__(256)
void cvt_f16_kernel(const float* __restrict__ query, const float* __restrict__ keys,
                    const float* __restrict__ Wq,    const float* __restrict__ Wk,
                    const float* __restrict__ vatt,
                    uint2* __restrict__ dst, float* __restrict__ wtab)
{
    if (blockIdx.x == 4096) {
        const int t = threadIdx.x;
        wtab[t] = -2.f * vatt[t]; wtab[t + 256] = -2.f * vatt[t + 256];
        return;
    }
    const int i4 = blockIdx.x * 256 + threadIdx.x;
    const float* src; int base;
    if (i4 < 262144)      { src = query; base = 0; }
    else if (i4 < 786432) { src = keys;  base = 262144; }
    else if (i4 < 917504) { src = Wq;    base = 786432; }
    else                  { src = Wk;    base = 917504; }
    const float4 v = *reinterpret_cast<const float4*>(src + (size_t)(i4 - base) * 4);
    dst[i4] = make_uint2(pk2(v.x, v.y), pk2(v.z, v.w));
}

// ---------------------------------------------------------------------------
// fp16 MFMA projection GEMM — exact R9 kernel (validated; pqT/pkT n-major).
// ---------------------------------------------------------------------------
__global__ __launch_bounds__(256)
void proj_mfma_kernel(const _Float16* __restrict__ X16,
                      float* __restrict__ pqT, float* __restrict__ pkT)
{
    __shared__ __align__(16) unsigned char smem[24576];   // 2 x (A 8KB + B 4KB)

    const int bid = (blockIdx.x & 7) * 48 + (blockIdx.x >> 3);

    int Bi, mt, tt, tkshift;
    const _Float16 *Wb, *Xb; float* Y;
    if (bid < 128) {      // query GEMM
        Bi = bid >> 6; mt = (bid >> 4) & 3; tt = bid & 15;
        Xb = X16 + ((size_t)Bi * 1024 + tt * 64) * 512;
        Wb = X16 + 3145728 + (size_t)Bi * 262144 + (size_t)(mt * 128) * 512;
        Y = pqT; tkshift = 6;
    } else {              // keys GEMM
        const int b2 = bid - 128;
        Bi = b2 >> 7; mt = (b2 >> 5) & 3; tt = b2 & 31;
        Xb = X16 + 1048576 + ((size_t)Bi * 2048 + tt * 64) * 512;
        Wb = X16 + 3670016 + (size_t)Bi * 262144 + (size_t)(mt * 128) * 512;
        Y = pkT; tkshift = 7;
    }
    const int tid = threadIdx.x;

    auto srcoff = [](int u) {
        const int row = u >> 2, s = (u & 3) ^ ((row >> 1) & 3);
        return (size_t)row * 512 + s * 8;
    };
    const _Float16* gA0 = Wb + srcoff(tid);
    const _Float16* gA1 = Wb + srcoff(tid + 256);
    const _Float16* gB  = Xb + srcoff(tid);
    unsigned char* const ldsA0 = smem + tid * 16;
    unsigned char* const ldsA1 = smem + 4096 + tid * 16;
    unsigned char* const ldsB  = smem + 8192 + tid * 16;

    const int wid = tid >> 6, lane = tid & 63;
    const int wm = wid >> 1, wn = wid & 1;
    const int r31 = lane & 31, h = lane >> 5;
    auto lofs = [](int row, int slot) {
        return row * 64 + ((slot ^ ((row >> 1) & 3)) * 16);
    };
    const int rowA0 = wm * 64 + r31, rowA1 = rowA0 + 32, rowB = wn * 32 + r31;
    const int a00 = lofs(rowA0, h),     a01 = lofs(rowA0, 2 + h);
    const int a10 = lofs(rowA1, h),     a11 = lofs(rowA1, 2 + h);
    const int b0  = 8192 + lofs(rowB, h), b1 = 8192 + lofs(rowB, 2 + h);

    f32x16 acc0, acc1;
#pragma unroll
    for (int i = 0; i < 16; ++i) { acc0[i] = 0.f; acc1[i] = 0.f; }

    GL2LDS16(gA0, ldsA0);
    GL2LDS16(gA1, ldsA1);
    GL2LDS16(gB,  ldsB);
    asm volatile("s_waitcnt vmcnt(0)" ::: "memory");
    __builtin_amdgcn_s_barrier();

    for (int ks = 0; ks < 16; ++ks) {
        const int buf = ks & 1;
        if (ks < 15) {
            const int ko = (ks + 1) * 32, bo = (buf ^ 1) * 12288;
            GL2LDS16(gA0 + ko, ldsA0 + bo);
            GL2LDS16(gA1 + ko, ldsA1 + bo);
            GL2LDS16(gB  + ko, ldsB  + bo);
        }
        const unsigned char* sb = smem + buf * 12288;
        const f16x8 fa00 = *reinterpret_cast<const f16x8*>(sb + a00);
        const f16x8 fa01 = *reinterpret_cast<const f16x8*>(sb + a01);
        const f16x8 fa10 = *reinterpret_cast<const f16x8*>(sb + a10);
        const f16x8 fa11 = *reinterpret_cast<const f16x8*>(sb + a11);
        const f16x8 fb0  = *reinterpret_cast<const f16x8*>(sb + b0);
        const f16x8 fb1  = *reinterpret_cast<const f16x8*>(sb + b1);
        acc0 = __builtin_amdgcn_mfma_f32_32x32x16_f16(fa00, fb0, acc0, 0, 0, 0);
        acc0 = __builtin_amdgcn_mfma_f32_32x32x16_f16(fa01, fb1, acc0, 0, 0, 0);
        acc1 = __builtin_amdgcn_mfma_f32_32x32x16_f16(fa10, fb0, acc1, 0, 0, 0);
        acc1 = __builtin_amdgcn_mfma_f32_32x32x16_f16(fa11, fb1, acc1, 0, 0, 0);
        if (ks < 15) {
            asm volatile("s_waitcnt vmcnt(0)" ::: "memory");
            __builtin_amdgcn_s_barrier();
        }
    }

    const int TK = 1 << tkshift;
    const int trow = tt * 64 + wn * 32 + r31;
    const int slice = Bi * 16 + (trow >> tkshift);
    const int t = trow & (TK - 1);
    const int nf0 = mt * 128 + wm * 64 + 4 * h;
#pragma unroll
    for (int ab = 0; ab < 2; ++ab) {
        const f32x16 acc = ab ? acc1 : acc0;
#pragma unroll
        for (int reg = 0; reg < 16; ++reg) {
            const int nf = nf0 + ab * 32 + (reg & 3) + 8 * (reg >> 2);
            Y[((size_t)(slice * 512 + nf) << tkshift) + t] = acc[reg] * C2;
        }
    }
}

// ---------------------------------------------------------------------------
// Fused score + softmax + context.  256 blocks x 1024 threads.
// Block = (slice, q-tile of 8). Thread (k = tid&127, nh = tid>>7): 64 n x 8 q.
// R9 structure (direct L2 pk, scalar pq/w) with q-amortization: per-n loads
// (1 vec + 3 s_load) serve 8 elements. Single-level partial combine.
// ---------------------------------------------------------------------------
__global__ __launch_bounds__(1024)
void score_ctx_kernel(const float* __restrict__ pqT,   // [32][512][64]
                      const float* __restrict__ pkT,   // [32][512][128]
                      const float* __restrict__ wtab,  // [512] = -2v
                      const float* __restrict__ keys,  // [32][128][512]
                      float* __restrict__ sc_out,      // [32][64][128]
                      float* __restrict__ ctx)         // [32][64][512]
{
    // bijective XCD swizzle (256 blocks): xcd owns 32 blocks = 4 slices
    const int wg = (blockIdx.x & 7) * 32 + (blockIdx.x >> 3);
    const int slice = wg >> 3;
    const int q0    = (wg & 7) * 8;
    const int tid   = threadIdx.x;
    const int k     = tid & 127;
    const int nh    = tid >> 7;   // 0..7

    __shared__ __align__(16) float shbuf[16384];   // 64KB: partial[8][8][128] / ctx tree
    __shared__ float scP[8][128];                  // 4KB
    __shared__ float red[16], red2[16];

    // wave-uniform scalar bases
    const int wv = __builtin_amdgcn_readfirstlane(nh);
    const float* __restrict__ pqb = pqT + ((size_t)slice * 512 + wv * 64) * 64 + q0;
    const float* __restrict__ wb  = wtab + wv * 64;
    const float* __restrict__ pkp = pkT + ((size_t)slice * 512 + wv * 64) * 128 + k;

    float acc[8];
#pragma unroll
    for (int i = 0; i < 8; ++i) acc[i] = 0.f;

#pragma unroll 8
    for (int n = 0; n < 64; ++n) {
        const float pk = pkp[(size_t)n * 128];                              // vector (L2)
        const float4 pA = *reinterpret_cast<const float4*>(pqb + n * 64);     // s_load x4
        const float4 pB = *reinterpret_cast<const float4*>(pqb + n * 64 + 4); // s_load x4
        const float w  = wb[n];                                             // s_load
        const float eA0 = __builtin_amdgcn_exp2f(pA.x + pk) + 1.f;
        const float eA1 = __builtin_amdgcn_exp2f(pA.y + pk) + 1.f;
        const float eA2 = __builtin_amdgcn_exp2f(pA.z + pk) + 1.f;
        const float eA3 = __builtin_amdgcn_exp2f(pA.w + pk) + 1.f;
        const float eB0 = __builtin_amdgcn_exp2f(pB.x + pk) + 1.f;
        const float eB1 = __builtin_amdgcn_exp2f(pB.y + pk) + 1.f;
        const float eB2 = __builtin_amdgcn_exp2f(pB.z + pk) + 1.f;
        const float eB3 = __builtin_amdgcn_exp2f(pB.w + pk) + 1.f;
        acc[0] = fmaf(w, __builtin_amdgcn_rcpf(eA0), acc[0]);   // trans
        acc[1] = fmaf(w, rcp_nr(eA1), acc[1]);                  // VALU
        acc[2] = fmaf(w, __builtin_amdgcn_rcpf(eA2), acc[2]);   // trans
        acc[3] = fmaf(w, rcp_nr(eA3), acc[3]);                  // VALU
        acc[4] = fmaf(w, __builtin_amdgcn_rcpf(eB0), acc[4]);   // trans
        acc[5] = fmaf(w, rcp_nr(eB1), acc[5]);                  // VALU
        acc[6] = fmaf(w, __builtin_amdgcn_rcpf(eB2), acc[6]);   // trans
        acc[7] = fmaf(w, rcp_nr(eB3), acc[7]);                  // VALU
    }

    // single-level combine: all 8 nh write their slab; thread (j=nh,k) sums 8
    {
        float (*partial)[8][128] = reinterpret_cast<float (*)[8][128]>(shbuf);
#pragma unroll
        for (int q = 0; q < 8; ++q) partial[nh][q][k] = acc[q];
        __syncthreads();
        float s = 0.f;
#pragma unroll
        for (int p = 0; p < 8; ++p) s += partial[p][nh][k];

        // softmax over k=128 for q-row j = nh (2 waves per row); sumv dropped
        const int wid = tid >> 6;
        const float m0 = wave_rmax(s);
        if ((tid & 63) == 0) red[wid] = m0;
        __syncthreads();
        const float m = fmaxf(red[2 * nh], red[2 * nh + 1]);
        const float e = __builtin_amdgcn_exp2f((s - m) * LOG2E);
        const float s0 = wave_rsum(e);
        if ((tid & 63) == 0) red2[wid] = s0;
        __syncthreads();
        const float ssum = red2[2 * nh] + red2[2 * nh + 1];
        const float p = e * __builtin_amdgcn_rcpf(ssum);
        sc_out[((size_t)(slice * 64 + q0 + nh)) * 128 + k] = p;
        scP[nh][k] = p;
    }
    __syncthreads();

    // context: kg = nh owns 16 k-rows; kv row loaded once, applied to 8 q's
    const int kg = nh, n4 = k;
    float4 cacc[8];
#pragma unroll
    for (int i = 0; i < 8; ++i) cacc[i] = make_float4(0.f, 0.f, 0.f, 0.f);
    const float* __restrict__ kb = keys + (size_t)slice * 65536 + (size_t)(kg * 16) * 512 + n4 * 4;
#pragma unroll 4
    for (int r = 0; r < 16; ++r) {
        const float4 kv = *reinterpret_cast<const float4*>(kb + (size_t)r * 512);
#pragma unroll
        for (int qq = 0; qq < 8; ++qq) {
            const float pv = scP[qq][kg * 16 + r];              // broadcast
            cacc[qq].x = fmaf(pv, kv.x, cacc[qq].x);
            cacc[qq].y = fmaf(pv, kv.y, cacc[qq].y);
            cacc[qq].z = fmaf(pv, kv.z, cacc[qq].z);
            cacc[qq].w = fmaf(pv, kv.w, cacc[qq].w);
        }
    }

    // tree-combine 8 kg-groups (shbuf as float4[4][8][128] = 64KB)
    float4* ctxp = reinterpret_cast<float4*>(shbuf);
    if (kg >= 4) {
#pragma unroll
        for (int qq = 0; qq < 8; ++qq) ctxp[((kg - 4) * 8 + qq) * 128 + n4] = cacc[qq];
    }
    __syncthreads();
    if (kg < 4) {
#pragma unroll
        for (int qq = 0; qq < 8; ++qq) {
            const float4 o = ctxp[(kg * 8 + qq) * 128 + n4];
            cacc[qq].x += o.x; cacc[qq].y += o.y; cacc[qq].z += o.z; cacc[qq].w += o.w;
        }
    }
    __syncthreads();
    if (kg == 2 || kg == 3) {
#pragma unroll
        for (int qq = 0; qq < 8; ++qq) ctxp[((kg - 2) * 8 + qq) * 128 + n4] = cacc[qq];
    }
    __syncthreads();
    if (kg < 2) {
#pragma unroll
        for (int qq = 0; qq < 8; ++qq) {
            const float4 o = ctxp[(kg * 8 + qq) * 128 + n4];
            cacc[qq].x += o.x; cacc[qq].y += o.y; cacc[qq].z += o.z; cacc[qq].w += o.w;
        }
    }
    __syncthreads();
    if (kg == 1) {
#pragma unroll
        for (int qq = 0; qq < 8; ++qq) ctxp[qq * 128 + n4] = cacc[qq];
    }
    __syncthreads();
    if (kg == 0) {
#pragma unroll
        for (int qq = 0; qq < 8; ++qq) {
            const float4 o = ctxp[qq * 128 + n4];
            cacc[qq].x += o.x; cacc[qq].y += o.y; cacc[qq].z += o.z; cacc[qq].w += o.w;
            *reinterpret_cast<float4*>(
                ctx + ((size_t)(slice * 64 + q0 + qq)) * 512 + n4 * 4) = cacc[qq];
        }
    }
}

// ---------------------------------------------------------------------------
extern "C" void kernel_launch(void* const* d_in, const int* in_sizes, int n_in,
                              void* d_out, int out_size, void* d_ws, size_t ws_size,
                              hipStream_t stream)
{
    const float* query = (const float*)d_in[0];
    const float* keys  = (const float*)d_in[1];
    const float* Wq    = (const float*)d_in[2];
    const float* Wk    = (const float*)d_in[3];
    const float* vatt  = (const float*)d_in[4];

    float* ctx_out = (float*)d_out;
    float* sc_out  = ctx_out + (size_t)32 * 64 * 512;

    float* pqT = (float*)d_ws;                                    // 4MB  [32][512][64]
    float* pkT = pqT + (size_t)32 * 512 * 64;                     // 8MB  [32][512][128]
    _Float16* X16 = (_Float16*)((char*)d_ws + 12 * 1024 * 1024);  // 8MB f16
    float* wtab = (float*)((char*)d_ws + 20 * 1024 * 1024);       // 512 f32

    cvt_f16_kernel<<<dim3(4097), 256, 0, stream>>>(query, keys, Wq, Wk, vatt,
                                                   (uint2*)X16, wtab);
    proj_mfma_kernel<<<dim3(384), 256, 0, stream>>>(X16, pqT, pkT);
    score_ctx_kernel<<<dim3(256), 1024, 0, stream>>>(pqT, pkT, wtab, keys, sc_out, ctx_out);
}

// Round 13
// 53.878 us; speedup vs baseline: 1.3276x; 1.1082x over previous
//
#include <hip/hip_runtime.h>

// Problem dims: B=2, b=16, t_q=64, t_k=128, d=512, slices = 32
// d_out = context [32][64][512] f32 ++ scores_normalized [32][64][128] f32
// d_ws: pqT [32][512][64] (4MB) ++ pkT [32][512][128] (8MB) ++ X16 (8MB f16)
//       ++ wtab[512] (@20MB: -2*vatt)

#define DEV_INLINE __device__ __forceinline__

constexpr float C2    = 2.8853900817779268f;  // 2*log2(e)
constexpr float LOG2E = 1.4426950408889634f;

typedef _Float16 f16x8 __attribute__((ext_vector_type(8)));
typedef float    f32x16 __attribute__((ext_vector_type(16)));

DEV_INLINE unsigned int pk2(float a, float b) {
    auto h = __builtin_amdgcn_cvt_pkrtz(a, b);
    return __builtin_bit_cast(unsigned int, h);
}

// Newton reciprocal: pure-VALU replacement for v_rcp_f32 (rel err ~6e-6)
DEV_INLINE float rcp_nr(float d) {
    float y = __builtin_bit_cast(float, 0x7EF311C3u - __builtin_bit_cast(unsigned int, d));
    y = y * (2.0f - d * y);
    y = y * (2.0f - d * y);
    return y;
}

#define GL2LDS16(g, l) __builtin_amdgcn_global_load_lds( \
    (const __attribute__((address_space(1))) void*)(g),  \
    (__attribute__((address_space(3))) void*)(l), 16, 0, 0)

DEV_INLINE float wave_rsum(float v) {
#pragma unroll
    for (int off = 32; off; off >>= 1) v += __shfl_xor(v, off, 64);
    return v;
}
DEV_INLINE float wave_rmax(float v) {
#pragma unroll
    for (int off = 32; off; off >>= 1) v = fmaxf(v, __shfl_xor(v, off, 64));
    return v;
}

// ---------------------------------------------------------------------------
// One-shot f32 -> f16 conversion + wtab (-2v) build (block 4096).
// ---------------------------------------------------------------------------
__global__ __launch_bounds__(256)
void cvt_f16_kernel(const float* __restrict__ query, const float* __restrict__ keys,
                    const float* __restrict__ Wq,    const float* __restrict__ Wk,
                    const float* __restrict__ vatt,
                    uint2* __restrict__ dst, float* __restrict__ wtab)
{
    if (blockIdx.x == 4096) {     // wtab: -2*v table (sumv dropped: softmax shift-inv)
        const int t = threadIdx.x;
        wtab[t] = -2.f * vatt[t]; wtab[t + 256] = -2.f * vatt[t + 256];
        return;
    }
    const int i4 = blockIdx.x * 256 + threadIdx.x;      // 0 .. 1,048,575
    const float* src; int base;
    if (i4 < 262144)      { src = query; base = 0; }
    else if (i4 < 786432) { src = keys;  base = 262144; }
    else if (i4 < 917504) { src = Wq;    base = 786432; }
    else                  { src = Wk;    base = 917504; }
    const float4 v = *reinterpret_cast<const float4*>(src + (size_t)(i4 - base) * 4);
    dst[i4] = make_uint2(pk2(v.x, v.y), pk2(v.z, v.w));
}

// ---------------------------------------------------------------------------
// fp16 MFMA projection GEMM (unchanged — validated R4-R12).
// ---------------------------------------------------------------------------
__global__ __launch_bounds__(256)
void proj_mfma_kernel(const _Float16* __restrict__ X16,
                      float* __restrict__ pqT, float* __restrict__ pkT)
{
    __shared__ __align__(16) unsigned char smem[24576];   // 2 x (A 8KB + B 4KB)

    const int bid = (blockIdx.x & 7) * 48 + (blockIdx.x >> 3);

    int Bi, mt, tt, tkshift;
    const _Float16 *Wb, *Xb; float* Y;
    if (bid < 128) {      // query GEMM
        Bi = bid >> 6; mt = (bid >> 4) & 3; tt = bid & 15;
        Xb = X16 + ((size_t)Bi * 1024 + tt * 64) * 512;
        Wb = X16 + 3145728 + (size_t)Bi * 262144 + (size_t)(mt * 128) * 512;
        Y = pqT; tkshift = 6;
    } else {              // keys GEMM
        const int b2 = bid - 128;
        Bi = b2 >> 7; mt = (b2 >> 5) & 3; tt = b2 & 31;
        Xb = X16 + 1048576 + ((size_t)Bi * 2048 + tt * 64) * 512;
        Wb = X16 + 3670016 + (size_t)Bi * 262144 + (size_t)(mt * 128) * 512;
        Y = pkT; tkshift = 7;
    }
    const int tid = threadIdx.x;

    auto srcoff = [](int u) {
        const int row = u >> 2, s = (u & 3) ^ ((row >> 1) & 3);
        return (size_t)row * 512 + s * 8;
    };
    const _Float16* gA0 = Wb + srcoff(tid);
    const _Float16* gA1 = Wb + srcoff(tid + 256);
    const _Float16* gB  = Xb + srcoff(tid);
    unsigned char* const ldsA0 = smem + tid * 16;
    unsigned char* const ldsA1 = smem + 4096 + tid * 16;
    unsigned char* const ldsB  = smem + 8192 + tid * 16;

    const int wid = tid >> 6, lane = tid & 63;
    const int wm = wid >> 1, wn = wid & 1;
    const int r31 = lane & 31, h = lane >> 5;
    auto lofs = [](int row, int slot) {
        return row * 64 + ((slot ^ ((row >> 1) & 3)) * 16);
    };
    const int rowA0 = wm * 64 + r31, rowA1 = rowA0 + 32, rowB = wn * 32 + r31;
    const int a00 = lofs(rowA0, h),     a01 = lofs(rowA0, 2 + h);
    const int a10 = lofs(rowA1, h),     a11 = lofs(rowA1, 2 + h);
    const int b0  = 8192 + lofs(rowB, h), b1 = 8192 + lofs(rowB, 2 + h);

    f32x16 acc0, acc1;
#pragma unroll
    for (int i = 0; i < 16; ++i) { acc0[i] = 0.f; acc1[i] = 0.f; }

    GL2LDS16(gA0, ldsA0);
    GL2LDS16(gA1, ldsA1);
    GL2LDS16(gB,  ldsB);
    asm volatile("s_waitcnt vmcnt(0)" ::: "memory");
    __builtin_amdgcn_s_barrier();

    for (int ks = 0; ks < 16; ++ks) {
        const int buf = ks & 1;
        if (ks < 15) {
            const int ko = (ks + 1) * 32, bo = (buf ^ 1) * 12288;
            GL2LDS16(gA0 + ko, ldsA0 + bo);
            GL2LDS16(gA1 + ko, ldsA1 + bo);
            GL2LDS16(gB  + ko, ldsB  + bo);
        }
        const unsigned char* sb = smem + buf * 12288;
        const f16x8 fa00 = *reinterpret_cast<const f16x8*>(sb + a00);
        const f16x8 fa01 = *reinterpret_cast<const f16x8*>(sb + a01);
        const f16x8 fa10 = *reinterpret_cast<const f16x8*>(sb + a10);
        const f16x8 fa11 = *reinterpret_cast<const f16x8*>(sb + a11);
        const f16x8 fb0  = *reinterpret_cast<const f16x8*>(sb + b0);
        const f16x8 fb1  = *reinterpret_cast<const f16x8*>(sb + b1);
        acc0 = __builtin_amdgcn_mfma_f32_32x32x16_f16(fa00, fb0, acc0, 0, 0, 0);
        acc0 = __builtin_amdgcn_mfma_f32_32x32x16_f16(fa01, fb1, acc0, 0, 0, 0);
        acc1 = __builtin_amdgcn_mfma_f32_32x32x16_f16(fa10, fb0, acc1, 0, 0, 0);
        acc1 = __builtin_amdgcn_mfma_f32_32x32x16_f16(fa11, fb1, acc1, 0, 0, 0);
        if (ks < 15) {
            asm volatile("s_waitcnt vmcnt(0)" ::: "memory");
            __builtin_amdgcn_s_barrier();
        }
    }

    const int TK = 1 << tkshift;
    const int trow = tt * 64 + wn * 32 + r31;
    const int slice = Bi * 16 + (trow >> tkshift);
    const int t = trow & (TK - 1);
    const int nf0 = mt * 128 + wm * 64 + 4 * h;
#pragma unroll
    for (int ab = 0; ab < 2; ++ab) {
        const f32x16 acc = ab ? acc1 : acc0;
#pragma unroll
        for (int reg = 0; reg < 16; ++reg) {
            const int nf = nf0 + ab * 32 + (reg & 3) + 8 * (reg >> 2);
            Y[((size_t)(slice * 512 + nf) << tkshift) + t] = acc[reg] * C2;
        }
    }
}

// ---------------------------------------------------------------------------
// Fused score + softmax + context — exact R9 structure (best measured: 54.1
// total), sumv machinery removed (softmax shift-invariant).
// 512 blocks x 1024 threads; q-tile of 4; nh = tid>>7 splits n 8-ways.
// Score loop: wave-uniform scalar pq/w loads, direct L2 pk, 2xNR + 2x v_rcp.
// ---------------------------------------------------------------------------
__global__ __launch_bounds__(1024)
void score_ctx_kernel(const float* __restrict__ pqT,   // [32][512][64]
                      const float* __restrict__ pkT,   // [32][512][128]
                      const float* __restrict__ wtab,  // [512] = -2v
                      const float* __restrict__ keys,  // [32][128][512]
                      float* __restrict__ sc_out,      // [32][64][128]
                      float* __restrict__ ctx)         // [32][64][512]
{
    // bijective XCD swizzle: xcd owns 4 slices
    const int xcd = blockIdx.x & 7, ix = blockIdx.x >> 3;
    const int slice = xcd * 4 + (ix >> 4);
    const int q0    = (ix & 15) * 4;
    const int tid   = threadIdx.x;
    const int k     = tid & 127;
    const int nh    = tid >> 7;   // 0..7

    __shared__ float partial[7][4][128];              // 14KB
    __shared__ __align__(16) float scQ[4][128];       // 2KB  (q-major)
    __shared__ __align__(16) float4 ctxp[4][4][128];  // 32KB context tree
    __shared__ float wredm[8], wreds[8];

    // wave-uniform scalar bases for pq4 / w
    const int wv = __builtin_amdgcn_readfirstlane(nh);
    const float* __restrict__ pqb = pqT + ((size_t)slice * 512 + wv * 64) * 64 + q0;
    const float* __restrict__ wb  = wtab + wv * 64;
    const float* __restrict__ pkp = pkT + ((size_t)slice * 512 + wv * 64) * 128 + k;

    float a0 = 0.f, a1 = 0.f, a2 = 0.f, a3 = 0.f;
#pragma unroll 8
    for (int n = 0; n < 64; ++n) {
        const float pk = pkp[(size_t)n * 128];                          // vector (L2)
        const float4 pq = *reinterpret_cast<const float4*>(pqb + n * 64); // s_load_dwordx4
        const float w = wb[n];                                          // s_load
        const float e0 = __builtin_amdgcn_exp2f(pq.x + pk) + 1.f;
        const float e1 = __builtin_amdgcn_exp2f(pq.y + pk) + 1.f;
        const float e2 = __builtin_amdgcn_exp2f(pq.z + pk) + 1.f;
        const float e3 = __builtin_amdgcn_exp2f(pq.w + pk) + 1.f;
        a0 = fmaf(w, rcp_nr(e0), a0);                    // VALU pipe
        a1 = fmaf(w, rcp_nr(e1), a1);                    // VALU pipe
        a2 = fmaf(w, __builtin_amdgcn_rcpf(e2), a2);     // trans pipe
        a3 = fmaf(w, __builtin_amdgcn_rcpf(e3), a3);     // trans pipe
    }
    if (nh) {
        partial[nh - 1][0][k] = a0; partial[nh - 1][1][k] = a1;
        partial[nh - 1][2][k] = a2; partial[nh - 1][3][k] = a3;
    }
    __syncthreads();
    if (!nh) {
        float s0 = a0, s1 = a1, s2 = a2, s3 = a3;     // sumv dropped (shift-inv)
#pragma unroll
        for (int p = 0; p < 7; ++p) {
            s0 += partial[p][0][k]; s1 += partial[p][1][k];
            s2 += partial[p][2][k]; s3 += partial[p][3][k];
        }
        scQ[0][k] = s0; scQ[1][k] = s1; scQ[2][k] = s2; scQ[3][k] = s3;
    }
    __syncthreads();

    // softmax over k=128 per q; threads < 512 active, j = nh&3
    {
        const int j = nh & 3;
        float e = 0.f;
        if (tid < 512) {
            const float orig = scQ[j][k];
            const float m0 = wave_rmax(orig);
            if ((tid & 63) == 0) wredm[tid >> 6] = m0;
            e = orig;
        }
        __syncthreads();
        if (tid < 512) {
            const float m = fmaxf(wredm[2 * j], wredm[2 * j + 1]);
            e = __builtin_amdgcn_exp2f((e - m) * LOG2E);
            const float ss = wave_rsum(e);
            if ((tid & 63) == 0) wreds[tid >> 6] = ss;
        }
        __syncthreads();
        if (tid < 512) {
            const float s = wreds[2 * j] + wreds[2 * j + 1];
            const float p = e * __builtin_amdgcn_rcpf(s);
            sc_out[((size_t)slice * 64 + q0 + j) * 128 + k] = p;
            scQ[j][k] = p;
        }
    }
    __syncthreads();

    // context: kg owns 16 k-rows; kv loaded once per 4 q's; broadcast prob reads
    const int kg = nh, n4 = k;
    float4 acc0 = {0,0,0,0}, acc1 = {0,0,0,0}, acc2 = {0,0,0,0}, acc3 = {0,0,0,0};
    const float* __restrict__ kb = keys + (size_t)slice * 65536 + (size_t)(kg * 16) * 512 + n4 * 4;
#pragma unroll
    for (int r4 = 0; r4 < 4; ++r4) {
        const float4 pv0 = *reinterpret_cast<const float4*>(&scQ[0][kg * 16 + r4 * 4]);
        const float4 pv1 = *reinterpret_cast<const float4*>(&scQ[1][kg * 16 + r4 * 4]);
        const float4 pv2 = *reinterpret_cast<const float4*>(&scQ[2][kg * 16 + r4 * 4]);
        const float4 pv3 = *reinterpret_cast<const float4*>(&scQ[3][kg * 16 + r4 * 4]);
        const float pa[4][4] = {{pv0.x, pv0.y, pv0.z, pv0.w},
                                {pv1.x, pv1.y, pv1.z, pv1.w},
                                {pv2.x, pv2.y, pv2.z, pv2.w},
                                {pv3.x, pv3.y, pv3.z, pv3.w}};
#pragma unroll
        for (int rr = 0; rr < 4; ++rr) {
            const float4 kv = *reinterpret_cast<const float4*>(kb + (size_t)(r4 * 4 + rr) * 512);
            acc0.x = fmaf(pa[0][rr], kv.x, acc0.x); acc0.y = fmaf(pa[0][rr], kv.y, acc0.y);
            acc0.z = fmaf(pa[0][rr], kv.z, acc0.z); acc0.w = fmaf(pa[0][rr], kv.w, acc0.w);
            acc1.x = fmaf(pa[1][rr], kv.x, acc1.x); acc1.y = fmaf(pa[1][rr], kv.y, acc1.y);
            acc1.z = fmaf(pa[1][rr], kv.z, acc1.z); acc1.w = fmaf(pa[1][rr], kv.w, acc1.w);
            acc2.x = fmaf(pa[2][rr], kv.x, acc2.x); acc2.y = fmaf(pa[2][rr], kv.y, acc2.y);
            acc2.z = fmaf(pa[2][rr], kv.z, acc2.z); acc2.w = fmaf(pa[2][rr], kv.w, acc2.w);
            acc3.x = fmaf(pa[3][rr], kv.x, acc3.x); acc3.y = fmaf(pa[3][rr], kv.y, acc3.y);
            acc3.z = fmaf(pa[3][rr], kv.z, acc3.z); acc3.w = fmaf(pa[3][rr], kv.w, acc3.w);
        }
    }

    // tree-combine 8 kg-groups -> kg 0, then store
    if (kg >= 4) {
        ctxp[kg - 4][0][n4] = acc0; ctxp[kg - 4][1][n4] = acc1;
        ctxp[kg - 4][2][n4] = acc2; ctxp[kg - 4][3][n4] = acc3;
    }
    __syncthreads();
    if (kg < 4) {
        const float4 o0 = ctxp[kg][0][n4], o1 = ctxp[kg][1][n4];
        const float4 o2 = ctxp[kg][2][n4], o3 = ctxp[kg][3][n4];
        acc0.x += o0.x; acc0.y += o0.y; acc0.z += o0.z; acc0.w += o0.w;
        acc1.x += o1.x; acc1.y += o1.y; acc1.z += o1.z; acc1.w += o1.w;
        acc2.x += o2.x; acc2.y += o2.y; acc2.z += o2.z; acc2.w += o2.w;
        acc3.x += o3.x; acc3.y += o3.y; acc3.z += o3.z; acc3.w += o3.w;
    }
    __syncthreads();
    if (kg == 2 || kg == 3) {
        ctxp[kg - 2][0][n4] = acc0; ctxp[kg - 2][1][n4] = acc1;
        ctxp[kg - 2][2][n4] = acc2; ctxp[kg - 2][3][n4] = acc3;
    }
    __syncthreads();
    if (kg < 2) {
        const float4 o0 = ctxp[kg][0][n4], o1 = ctxp[kg][1][n4];
        const float4 o2 = ctxp[kg][2][n4], o3 = ctxp[kg][3][n4];
        acc0.x += o0.x; acc0.y += o0.y; acc0.z += o0.z; acc0.w += o0.w;
        acc1.x += o1.x; acc1.y += o1.y; acc1.z += o1.z; acc1.w += o1.w;
        acc2.x += o2.x; acc2.y += o2.y; acc2.z += o2.z; acc2.w += o2.w;
        acc3.x += o3.x; acc3.y += o3.y; acc3.z += o3.z; acc3.w += o3.w;
    }
    __syncthreads();
    if (kg == 1) {
        ctxp[0][0][n4] = acc0; ctxp[0][1][n4] = acc1;
        ctxp[0][2][n4] = acc2; ctxp[0][3][n4] = acc3;
    }
    __syncthreads();
    if (kg == 0) {
        const float4 o0 = ctxp[0][0][n4], o1 = ctxp[0][1][n4];
        const float4 o2 = ctxp[0][2][n4], o3 = ctxp[0][3][n4];
        acc0.x += o0.x; acc0.y += o0.y; acc0.z += o0.z; acc0.w += o0.w;
        acc1.x += o1.x; acc1.y += o1.y; acc1.z += o1.z; acc1.w += o1.w;
        acc2.x += o2.x; acc2.y += o2.y; acc2.z += o2.z; acc2.w += o2.w;
        acc3.x += o3.x; acc3.y += o3.y; acc3.z += o3.z; acc3.w += o3.w;
        float* cb = ctx + ((size_t)slice * 64 + q0) * 512 + n4 * 4;
        *reinterpret_cast<float4*>(cb)             = acc0;
        *reinterpret_cast<float4*>(cb + 512)       = acc1;
        *reinterpret_cast<float4*>(cb + 2 * 512)   = acc2;
        *reinterpret_cast<float4*>(cb + 3 * 512)   = acc3;
    }
}

// ---------------------------------------------------------------------------
extern "C" void kernel_launch(void* const* d_in, const int* in_sizes, int n_in,
                              void* d_out, int out_size, void* d_ws, size_t ws_size,
                              hipStream_t stream)
{
    const float* query = (const float*)d_in[0];
    const float* keys  = (const float*)d_in[1];
    const float* Wq    = (const float*)d_in[2];
    const float* Wk    = (const float*)d_in[3];
    const float* vatt  = (const float*)d_in[4];

    float* ctx_out = (float*)d_out;
    float* sc_out  = ctx_out + (size_t)32 * 64 * 512;

    float* pqT = (float*)d_ws;                                    // 4MB
    float* pkT = pqT + (size_t)32 * 512 * 64;                     // 8MB
    _Float16* X16 = (_Float16*)((char*)d_ws + 12 * 1024 * 1024);  // 8MB f16
    float* wtab = (float*)((char*)d_ws + 20 * 1024 * 1024);       // 512 f32

    cvt_f16_kernel<<<dim3(4097), 256, 0, stream>>>(query, keys, Wq, Wk, vatt,
                                                   (uint2*)X16, wtab);
    proj_mfma_kernel<<<dim3(384), 256, 0, stream>>>(X16, pqT, pkT);
    score_ctx_kernel<<<dim3(512), 1024, 0, stream>>>(pqT, pkT, wtab, keys, sc_out, ctx_out);
}